// Round 1
// baseline (181.045 us; speedup 1.0000x reference)
//
#include <hip/hip_runtime.h>

// Problem constants
#define T_ 128
#define B_ 64
#define NH_ 64
#define NC_ 10

__device__ __forceinline__ float sigmoid_f(float x) {
    return 1.0f / (1.0f + __expf(-x));
}
__device__ __forceinline__ float tanh_f(float x) {
    // tanh(x) = 1 - 2/(exp(2x)+1); stable at both extremes with __expf
    return 1.0f - 2.0f / (1.0f + __expf(2.0f * x));
}

// ---------------------------------------------------------------------------
// Kernel 1: per-frame 3x3 VALID conv -> sigmoid(logit - thr) -> spatial mean
// grid = 8192 frames, 256 threads
// ---------------------------------------------------------------------------
__global__ __launch_bounds__(256) void conv_feat(const float* __restrict__ img,
                                                 const float* __restrict__ cw,
                                                 const float* __restrict__ cb,
                                                 const float* __restrict__ thr,
                                                 float* __restrict__ feat) {
    __shared__ __align__(16) float im[64 * 64];
    const int f = blockIdx.x;
    const int tid = threadIdx.x;
    const float* src = img + (size_t)f * 4096;
#pragma unroll
    for (int i = 0; i < 4; i++) {
        *(float4*)&im[(i * 256 + tid) * 4] = *(const float4*)&src[(i * 256 + tid) * 4];
    }
    const float w0 = cw[0], w1 = cw[1], w2 = cw[2], w3 = cw[3], w4 = cw[4],
                w5 = cw[5], w6 = cw[6], w7 = cw[7], w8 = cw[8];
    const float bias = cb[0] - thr[0];
    __syncthreads();

    float sum = 0.0f;
#pragma unroll
    for (int i = 0; i < 16; i++) {
        int idx = i * 256 + tid;
        if (idx < 62 * 62) {
            int oy = idx / 62;
            int ox = idx - oy * 62;
            const float* p = &im[oy * 64 + ox];
            float acc = bias;
            acc = fmaf(p[0],   w0, acc);
            acc = fmaf(p[1],   w1, acc);
            acc = fmaf(p[2],   w2, acc);
            acc = fmaf(p[64],  w3, acc);
            acc = fmaf(p[65],  w4, acc);
            acc = fmaf(p[66],  w5, acc);
            acc = fmaf(p[128], w6, acc);
            acc = fmaf(p[129], w7, acc);
            acc = fmaf(p[130], w8, acc);
            sum += sigmoid_f(acc);
        }
    }
    // wave (64-lane) reduce, then cross-wave via LDS
#pragma unroll
    for (int off = 32; off >= 1; off >>= 1) sum += __shfl_down(sum, off, 64);
    __shared__ float wsum[4];
    const int wv = tid >> 6, ln = tid & 63;
    if (ln == 0) wsum[wv] = sum;
    __syncthreads();
    if (tid == 0) feat[f] = (wsum[0] + wsum[1] + wsum[2] + wsum[3]) * (1.0f / 3844.0f);
}

// ---------------------------------------------------------------------------
// Kernel 2: fuse per-gate fc+lw:  A_g = lw_g @ fc_g[:,1:], v_g = lw_g @ fc_g[:,0],
//           c_g = lw_g @ fc_b_g + lb_g.   grid = 4 gates, 256 threads
// ---------------------------------------------------------------------------
struct FuseArgs {
    const float* fcw[4];
    const float* fcb[4];
    const float* lw[4];
    const float* lb[4];
};

__global__ __launch_bounds__(256) void fuse_kernel(FuseArgs a, float* __restrict__ Aall,
                                                   float* __restrict__ Vall,
                                                   float* __restrict__ Call) {
    const int g = blockIdx.x;
    const float* fcw = a.fcw[g];  // [64][65]
    const float* fcb = a.fcb[g];  // [64]
    const float* lw  = a.lw[g];   // [64][64]
    const float* lb  = a.lb[g];   // [64]
    __shared__ float fcs[64 * 65];
    __shared__ float fbs[64];
    for (int i = threadIdx.x; i < 64 * 65; i += 256) fcs[i] = fcw[i];
    if (threadIdx.x < 64) fbs[threadIdx.x] = fcb[threadIdx.x];
    __syncthreads();

    const int n = threadIdx.x >> 2;         // 0..63 output row
    const int j0 = (threadIdx.x & 3) * 16;  // 16 columns per thread
    float lrow[64];
#pragma unroll
    for (int k = 0; k < 64; k++) lrow[k] = lw[n * 64 + k];

    for (int j = j0; j < j0 + 16; j++) {
        float s = 0.0f;
#pragma unroll
        for (int k = 0; k < 64; k++) s = fmaf(lrow[k], fcs[k * 65 + j + 1], s);
        Aall[(g * 64 + n) * 64 + j] = s;
    }
    if ((threadIdx.x & 3) == 0) {
        float sv = 0.0f, sc = 0.0f;
#pragma unroll
        for (int k = 0; k < 64; k++) {
            sv = fmaf(lrow[k], fcs[k * 65], sv);
            sc = fmaf(lrow[k], fbs[k], sc);
        }
        Vall[g * 64 + n] = sv;
        Call[g * 64 + n] = sc + lb[n];
    }
}

// ---------------------------------------------------------------------------
// Kernel 3: the sequential recurrence. One block per batch row (64 blocks),
// 256 threads = 4 waves; thread j owns gate g=j>>6, hidden n=j&63.
// Per-thread weights live in registers (W1: fused A row, W2: ew row).
// ---------------------------------------------------------------------------
__global__ __launch_bounds__(256, 1) void recur(
    const float* __restrict__ feat, const float* __restrict__ Aall,
    const float* __restrict__ Vall, const float* __restrict__ Call,
    const float* __restrict__ ew_f, const float* __restrict__ eb_f,
    const float* __restrict__ ew_i, const float* __restrict__ eb_i,
    const float* __restrict__ ew_u, const float* __restrict__ eb_u,
    const float* __restrict__ ew_o, const float* __restrict__ eb_o,
    float* __restrict__ outs) {
    const int b = blockIdx.x;
    const int tid = threadIdx.x;
    const int g = tid >> 6, n = tid & 63;
    const float* ew  = (g == 0) ? ew_f : (g == 1) ? ew_i : (g == 2) ? ew_u : ew_o;
    const float* ebp = (g == 0) ? eb_f : (g == 1) ? eb_i : (g == 2) ? eb_u : eb_o;

    float W1[64], W2[64];
#pragma unroll
    for (int k4 = 0; k4 < 16; k4++) {
        float4 av = *(const float4*)&Aall[tid * 64 + k4 * 4];
        W1[k4 * 4 + 0] = av.x; W1[k4 * 4 + 1] = av.y;
        W1[k4 * 4 + 2] = av.z; W1[k4 * 4 + 3] = av.w;
        float4 ev = *(const float4*)&ew[n * 64 + k4 * 4];
        W2[k4 * 4 + 0] = ev.x; W2[k4 * 4 + 1] = ev.y;
        W2[k4 * 4 + 2] = ev.z; W2[k4 * 4 + 3] = ev.w;
    }
    const float vj = Vall[tid], cj = Call[tid], ebj = ebp[n];

    __shared__ __align__(16) float hxs[64];
    __shared__ __align__(16) float qs[256];
    __shared__ __align__(16) float acts[256];
    __shared__ float xts[T_];
    for (int i = tid; i < T_; i += 256) xts[i] = feat[b * T_ + i];
    if (tid < 64) hxs[tid] = 0.0f;
    float cx = 0.0f;
    __syncthreads();

    for (int t = 0; t < T_; t++) {
        // stage 1: qout = tanh(xt*v + hx @ A^T + c)
        float a0 = 0, a1 = 0, a2 = 0, a3 = 0;
#pragma unroll
        for (int k4 = 0; k4 < 16; k4++) {
            float4 h = *(const float4*)&hxs[k4 * 4];  // broadcast read
            a0 = fmaf(W1[k4 * 4 + 0], h.x, a0);
            a1 = fmaf(W1[k4 * 4 + 1], h.y, a1);
            a2 = fmaf(W1[k4 * 4 + 2], h.z, a2);
            a3 = fmaf(W1[k4 * 4 + 3], h.w, a3);
        }
        const float q = tanh_f(fmaf(xts[t], vj, cj) + ((a0 + a1) + (a2 + a3)));
        qs[tid] = q;
        __syncthreads();

        // stage 2: z = qout * sigmoid(qout @ ew^T + eb); gate activation
        float s0 = 0, s1 = 0, s2 = 0, s3 = 0;
#pragma unroll
        for (int k4 = 0; k4 < 16; k4++) {
            float4 qv = *(const float4*)&qs[(g << 6) + k4 * 4];  // broadcast per wave
            s0 = fmaf(W2[k4 * 4 + 0], qv.x, s0);
            s1 = fmaf(W2[k4 * 4 + 1], qv.y, s1);
            s2 = fmaf(W2[k4 * 4 + 2], qv.z, s2);
            s3 = fmaf(W2[k4 * 4 + 3], qv.w, s3);
        }
        const float z = q * sigmoid_f(((s0 + s1) + (s2 + s3)) + ebj);
        const float act = (g == 2) ? tanh_f(z) : sigmoid_f(z);
        acts[tid] = act;
        __syncthreads();

        // cell update by threads 0..63 (one per hidden unit)
        if (tid < 64) {
            const float ff = acts[tid], ii = acts[64 + tid],
                        uu = acts[128 + tid], oo = acts[192 + tid];
            cx = fmaf(ff, cx, ii * uu);
            const float h = oo * tanh_f(cx);
            hxs[tid] = h;
            outs[((size_t)t * B_ + b) * NH_ + tid] = h;
        }
        __syncthreads();
    }
}

// ---------------------------------------------------------------------------
// Kernel 4: classifier  out[t,b,:] = h[t,b,:] @ cls_w^T + cls_b
// 256 threads = 4 waves; each wave handles one (t,b) row
// ---------------------------------------------------------------------------
__global__ __launch_bounds__(256) void classify(const float* __restrict__ outs,
                                                const float* __restrict__ cw,
                                                const float* __restrict__ cbias,
                                                float* __restrict__ out) {
    const int tid = threadIdx.x;
    const int r = tid >> 6, ln = tid & 63;
    const int row = blockIdx.x * 4 + r;  // 0..8191
    const float h = outs[(size_t)row * 64 + ln];
    float p[10];
#pragma unroll
    for (int c = 0; c < 10; c++) p[c] = h * cw[c * 64 + ln];
#pragma unroll
    for (int off = 32; off >= 1; off >>= 1) {
#pragma unroll
        for (int c = 0; c < 10; c++) p[c] += __shfl_xor(p[c], off, 64);
    }
    if (ln < 10) out[(size_t)row * 10 + ln] = p[ln] + cbias[ln];
}

// ---------------------------------------------------------------------------
extern "C" void kernel_launch(void* const* d_in, const int* in_sizes, int n_in,
                              void* d_out, int out_size, void* d_ws, size_t ws_size,
                              hipStream_t stream) {
    const float* images = (const float*)d_in[0];
    const float* thr    = (const float*)d_in[1];
    const float* convw  = (const float*)d_in[2];
    const float* convb  = (const float*)d_in[3];
    const float* fcw[4]; const float* fcb[4]; const float* lw[4]; const float* lb[4];
    const float* ew[4];  const float* eb[4];
    for (int g = 0; g < 4; g++) {
        int base = 4 + g * 6;
        fcw[g] = (const float*)d_in[base + 0];
        fcb[g] = (const float*)d_in[base + 1];
        lw[g]  = (const float*)d_in[base + 2];
        lb[g]  = (const float*)d_in[base + 3];
        ew[g]  = (const float*)d_in[base + 4];
        eb[g]  = (const float*)d_in[base + 5];
    }
    const float* clsw = (const float*)d_in[28];
    const float* clsb = (const float*)d_in[29];

    float* ws   = (float*)d_ws;
    float* feat = ws;            // 8192 floats
    float* Aall = ws + 8192;     // 16384 floats
    float* Vall = ws + 24576;    // 256
    float* Call = ws + 24832;    // 256
    float* outs = ws + 25088;    // 524288 floats (T*B*NH)

    conv_feat<<<8192, 256, 0, stream>>>(images, convw, convb, thr, feat);

    FuseArgs fa;
    for (int g = 0; g < 4; g++) {
        fa.fcw[g] = fcw[g]; fa.fcb[g] = fcb[g];
        fa.lw[g] = lw[g];   fa.lb[g] = lb[g];
    }
    fuse_kernel<<<4, 256, 0, stream>>>(fa, Aall, Vall, Call);

    recur<<<B_, 256, 0, stream>>>(feat, Aall, Vall, Call,
                                  ew[0], eb[0], ew[1], eb[1],
                                  ew[2], eb[2], ew[3], eb[3], outs);

    classify<<<2048, 256, 0, stream>>>(outs, clsw, clsb, (float*)d_out);
}